// Round 4
// baseline (243.420 us; speedup 1.0000x reference)
//
#include <hip/hip_runtime.h>

#define EG   16000   // graph edges
#define NG   1000    // graph_size (block rows/cols)
#define BB   32      // batch
#define SIZE 16000   // feature length (NG*16)
#define CAP  64      // bin capacity (Poisson(16): P(>64) < 1e-17, guarded)

// ---- extract: pack (t0,t1) headers of each edge tile into 64 KB ----
__global__ void extract_kernel(const int* __restrict__ rows,
                               const int* __restrict__ cols,
                               int* __restrict__ t01) {
    int e = blockIdx.x * blockDim.x + threadIdx.x;
    if (e < EG) {
        int t0 = rows[e << 8] >> 4;          // rows[e*256] = t0*16
        int t1 = cols[e << 8] >> 4;          // cols[e*256] = t1*16
        t01[e] = (t0 << 10) | t1;            // t0,t1 < 1000 < 1024
    }
}

// ---- build: one wave per bin; deterministic ballot-compaction ----
// No atomics, no memset dependency: bins[g] and edge_of[g*64 .. g*64+bins[g])
// are unconditionally written every call, in ascending edge order.
__global__ __launch_bounds__(64) void build_kernel(const int* __restrict__ t01,
                                                   int* __restrict__ bins,
                                                   int* __restrict__ edge_of) {
    int g    = blockIdx.x;
    int lane = threadIdx.x;                  // 0..63; EG = 64*250 exact
    int cnt  = 0;
    for (int ebase = 0; ebase < EG; ebase += 64) {
        int e  = ebase + lane;
        int pk = t01[e];
        bool m = (pk >> 10) == g;
        unsigned long long mask = __ballot(m);
        if (m) {
            int rank = __popcll(mask & ((1ull << lane) - 1ull));
            int slot = cnt + rank;
            if (slot < CAP)
                edge_of[(g << 6) + slot] = e | ((pk & 1023) << 16);
        }
        cnt += __popcll(mask);
    }
    if (lane == 0) bins[g] = (cnt < CAP) ? cnt : CAP;
}

// ---- main kernel: one 256-thread workgroup per destination block-row ----
// Thread t owns outputs (b0, j) and (b0+16, j); j=t&15, b0=t>>4 (0..15).
// Sampling (eps*exp(lv)+mean) fused inline. No LDS, no barriers;
// edge header prefetched one iteration ahead.
__global__ __launch_bounds__(256) void spmm_kernel(
    const float* __restrict__ wm, const float* __restrict__ wlv,
    const float* __restrict__ ew, const float* __restrict__ x,
    const float* __restrict__ bm, const float* __restrict__ blv,
    const float* __restrict__ eb, const int* __restrict__ bins,
    const int* __restrict__ edge_of, float* __restrict__ out)
{
    int g   = blockIdx.x;
    int tid = threadIdx.x;
    int j   = tid & 15;
    int b0  = tid >> 4;                      // 0..15

    int n = bins[g];                         // already clamped to CAP
    const int* hp = edge_of + (g << 6);

    float a0 = 0.f, a1 = 0.f;
    int h = (n > 0) ? hp[0] : 0;

    for (int p = 0; p < n; ++p) {
        int hn = (p + 1 < n) ? hp[p + 1] : 0;   // prefetch next header
        int e  = h & 0xFFFF;
        int t1 = h >> 16;
        int base = (e << 8) + j;

        // sample weight column j of the 16x16 tile
        float W[16];
        #pragma unroll
        for (int i = 0; i < 16; ++i) {
            float m  = wm [base + (i << 4)];
            float lv = wlv[base + (i << 4)];
            float ep = ew [base + (i << 4)];
            W[i] = fmaf(ep, __expf(lv), m);
        }

        const float* xp = x + (t1 << 4);
        float4 X0[4], X1[4];
        #pragma unroll
        for (int q = 0; q < 4; ++q) {
            X0[q] = ((const float4*)(xp + (b0     ) * SIZE))[q];
            X1[q] = ((const float4*)(xp + (b0 + 16) * SIZE))[q];
        }
        const float* f0 = (const float*)X0;
        const float* f1 = (const float*)X1;
        #pragma unroll
        for (int i = 0; i < 16; ++i) {
            a0 = fmaf(W[i], f0[i], a0);
            a1 = fmaf(W[i], f1[i], a1);
        }
        h = hn;
    }

    int r = (g << 4) + j;
    float bias = fmaf(eb[r], __expf(blv[r]), bm[r]);
    out[(b0     ) * SIZE + r] = a0 + bias;
    out[(b0 + 16) * SIZE + r] = a1 + bias;
    if (g == 0 && tid == 0) out[BB * SIZE] = 0.0f;   // kl scalar
}

extern "C" void kernel_launch(void* const* d_in, const int* in_sizes, int n_in,
                              void* d_out, int out_size, void* d_ws, size_t ws_size,
                              hipStream_t stream) {
    const float* x   = (const float*)d_in[0];
    const float* wm  = (const float*)d_in[1];
    const float* wlv = (const float*)d_in[2];
    const float* bm  = (const float*)d_in[3];
    const float* blv = (const float*)d_in[4];
    const float* ew  = (const float*)d_in[5];
    const float* eb  = (const float*)d_in[6];
    const int* rows  = (const int*)d_in[7];
    const int* cols  = (const int*)d_in[8];
    float* out = (float*)d_out;

    char* ws = (char*)d_ws;
    int* t01     = (int*)(ws);               // 16000 ints (64 KB)
    int* bins    = (int*)(ws + 65536);       // 1000 ints
    int* edge_of = (int*)(ws + 69632);       // NG*CAP = 64000 ints (256 KB)

    extract_kernel<<<(EG + 255) / 256, 256, 0, stream>>>(rows, cols, t01);
    build_kernel<<<NG, 64, 0, stream>>>(t01, bins, edge_of);
    spmm_kernel<<<NG, 256, 0, stream>>>(wm, wlv, ew, x, bm, blv, eb,
                                        bins, edge_of, out);
}